// Round 8
// baseline (170.887 us; speedup 1.0000x reference)
//
#include <hip/hip_runtime.h>

// Problem dims
#define NB 32
#define NA 64
#define SLEN 256
#define NH 128
#define RLEN 64
#define NE 16

typedef _Float16 f16;
typedef _Float16 f16x8 __attribute__((ext_vector_type(8)));
typedef _Float16 f16x4 __attribute__((ext_vector_type(4)));
typedef float f32x4 __attribute__((ext_vector_type(4)));

__device__ inline f16x8 cvt8(float4 a, float4 b) {
  f16x8 r;
  r[0] = (f16)a.x; r[1] = (f16)a.y; r[2] = (f16)a.z; r[3] = (f16)a.w;
  r[4] = (f16)b.x; r[5] = (f16)b.y; r[6] = (f16)b.z; r[7] = (f16)b.w;
  return r;
}

__device__ inline void gload_lds16(const float* g, float* l) {
  __builtin_amdgcn_global_load_lds((const __attribute__((address_space(1))) void*)g,
                                   (__attribute__((address_space(3))) void*)l, 16, 0, 0);
}

// Gather one MFMA B-fragment directly from a raw row-major weight matrix.
// r[t] = W[row0 + t][col], t=0..7  (equivalent to the packed layout)
__device__ inline f16x8 gatherW(const float* __restrict__ W, int ld, int row0, int col) {
  f16x8 r;
#pragma unroll
  for (int t = 0; t < 8; ++t) r[t] = (f16)W[(size_t)(row0 + t) * ld + col];
  return r;
}

// ---------------------------------------------------------------------------
// KA: fused weight-pack (blocks 128..191) + k1m s-MLP (blocks 0..127).
// k1m path gathers se/re1b weight fragments directly (no pack dependency).
// Pack covers only k3/k5 weights: re_w1a, re_w2, ra_w, ae1b, ae1c, ae1a, ae2.
// ---------------------------------------------------------------------------
__global__ __launch_bounds__(256) void ka(const float* __restrict__ states,
                                          const float* __restrict__ se_w1,
                                          const float* __restrict__ se_b1,
                                          const float* __restrict__ se_w2,
                                          const float* __restrict__ se_b2,
                                          const float* __restrict__ re_w1,
                                          const float* __restrict__ re_b1,
                                          const float* __restrict__ re_w2,
                                          const float* __restrict__ ra_w,
                                          const float* __restrict__ ae_w1,
                                          const float* __restrict__ ae_w2,
                                          float* __restrict__ s_out,
                                          float* __restrict__ sp_pk,
                                          f16* __restrict__ pk) {
  __shared__ f16 t1[16 * 128];
  __shared__ f16 t2[16 * 128];
  if (blockIdx.x >= 128) {
    // ---- pack path ----
    int t0 = (blockIdx.x - 128) * 256 + threadIdx.x;
    for (int idx = t0; idx < 188416; idx += 64 * 256) {
      const float* src; int ro, N, ld, base, dst;
      if (idx < 8192)        { src = re_w1; ro = 0;   N = 128; ld = 128; base = 0;      dst = 0; }
      else if (idx < 40960)  { src = re_w2; ro = 0;   N = 256; ld = 256; base = 8192;   dst = 8192; }
      else if (idx < 90112)  { src = ra_w;  ro = 0;   N = 128; ld = 128; base = 40960;  dst = 106496; }
      else if (idx < 106496) { src = ae_w1; ro = 256; N = 128; ld = 128; base = 90112;  dst = 155648; }
      else if (idx < 122880) { src = ae_w1; ro = 384; N = 128; ld = 128; base = 106496; dst = 172032; }
      else if (idx < 155648) { src = ae_w1; ro = 0;   N = 128; ld = 128; base = 122880; dst = 188416; }
      else                   { src = ae_w2; ro = 0;   N = 256; ld = 256; base = 155648; dst = 221184; }
      int li = idx - base;
      int t = li & 7, l = (li >> 3) & 63, rem = li >> 9;
      int NT = N >> 4;
      int nt = rem % NT, kt = rem / NT;
      int k = kt * 32 + (l >> 4) * 8 + t;
      int n = nt * 16 + (l & 15);
      pk[dst + li] = (f16)src[(size_t)(ro + k) * ld + n];
    }
    return;
  }
  // ---- k1m path: 16 rows per block ----
  const int row0 = blockIdx.x * 16;
  const int tid = threadIdx.x;
  const int w = tid >> 6, l = tid & 63, lr = l & 15, lh = l >> 4;

  f32x4 acc[2];
  acc[0] = (f32x4){0.f, 0.f, 0.f, 0.f};
  acc[1] = (f32x4){0.f, 0.f, 0.f, 0.f};

  // layer1 K=256
#pragma unroll
  for (int kt = 0; kt < 8; ++kt) {
    const float* p = states + (size_t)(row0 + lr) * SLEN + kt * 32 + lh * 8;
    f16x8 aF = cvt8(*(const float4*)p, *(const float4*)(p + 4));
#pragma unroll
    for (int n = 0; n < 2; ++n) {
      f16x8 bF = gatherW(se_w1, 128, kt * 32 + lh * 8, (w * 2 + n) * 16 + lr);
      acc[n] = __builtin_amdgcn_mfma_f32_16x16x32_f16(aF, bF, acc[n], 0, 0, 0);
    }
  }
#pragma unroll
  for (int n = 0; n < 2; ++n) {
    int h = w * 32 + n * 16 + lr;
    float bias = se_b1[h];
#pragma unroll
    for (int reg = 0; reg < 4; ++reg) {
      int j = lh * 4 + reg;
      float v = fmaxf(acc[n][reg] + bias, 0.f);
      unsigned off = (unsigned)((j * NH + h) * 2) ^ ((unsigned)(j & 7) << 4);
      *(f16*)((char*)t1 + off) = (f16)v;
    }
  }
  __syncthreads();

  // layer2 K=128
  acc[0] = (f32x4){0.f, 0.f, 0.f, 0.f};
  acc[1] = (f32x4){0.f, 0.f, 0.f, 0.f};
#pragma unroll
  for (int kt = 0; kt < 4; ++kt) {
    unsigned off = (unsigned)((lr * NH + kt * 32 + lh * 8) * 2) ^ ((unsigned)(lr & 7) << 4);
    f16x8 aF = *(const f16x8*)((char*)t1 + off);
#pragma unroll
    for (int n = 0; n < 2; ++n) {
      f16x8 bF = gatherW(se_w2, 128, kt * 32 + lh * 8, (w * 2 + n) * 16 + lr);
      acc[n] = __builtin_amdgcn_mfma_f32_16x16x32_f16(aF, bF, acc[n], 0, 0, 0);
    }
  }
#pragma unroll
  for (int n = 0; n < 2; ++n) {
    int h = w * 32 + n * 16 + lr;
    float bias = se_b2[h];
#pragma unroll
    for (int reg = 0; reg < 4; ++reg) {
      int j = lh * 4 + reg;
      float v = fmaxf(acc[n][reg] + bias, 0.f);
      s_out[(size_t)(row0 + j) * NH + h] = v;
      unsigned off = (unsigned)((j * NH + h) * 2) ^ ((unsigned)(j & 7) << 4);
      *(f16*)((char*)t2 + off) = (f16)v;
    }
  }
  __syncthreads();

  // proj K=128: sproj1 = s @ re_w1[64:192] + re_b1, packed store in k3 C-frag order
  acc[0] = (f32x4){0.f, 0.f, 0.f, 0.f};
  acc[1] = (f32x4){0.f, 0.f, 0.f, 0.f};
#pragma unroll
  for (int kt = 0; kt < 4; ++kt) {
    unsigned off = (unsigned)((lr * NH + kt * 32 + lh * 8) * 2) ^ ((unsigned)(lr & 7) << 4);
    f16x8 aF = *(const f16x8*)((char*)t2 + off);
#pragma unroll
    for (int n = 0; n < 2; ++n) {
      f16x8 bF = gatherW(re_w1, 128, 64 + kt * 32 + lh * 8, (w * 2 + n) * 16 + lr);
      acc[n] = __builtin_amdgcn_mfma_f32_16x16x32_f16(aF, bF, acc[n], 0, 0, 0);
    }
  }
  const int bb = row0 >> 6;
  const int mtile = (row0 & 63) >> 4;
#pragma unroll
  for (int n = 0; n < 2; ++n) {
    int h = w * 32 + n * 16 + lr;
    float bias = re_b1[h];
    float4 outv;
#pragma unroll
    for (int reg = 0; reg < 4; ++reg) outv[reg] = acc[n][reg] + bias;
    *(float4*)(sp_pk + ((size_t)((bb * 4 + mtile) * 8 + w * 2 + n) * 64 + l) * 4) = outv;
  }
}

// ---------------------------------------------------------------------------
// K3 v5 (unchanged): 4 (b,i) tiles per block, grid 512. Relations
// double-buffered in LDS via global_load_lds with pre-swizzled source.
// ---------------------------------------------------------------------------
__global__ __launch_bounds__(256) void k3_rel(const float* __restrict__ relations,
                                              const float* __restrict__ alive_mask,
                                              const float* __restrict__ sp_pk,
                                              const float* __restrict__ re_b2,
                                              const f16* __restrict__ pw1,
                                              const f16* __restrict__ pw2,
                                              const int* __restrict__ agent_id,
                                              float* __restrict__ r_red,
                                              f16* __restrict__ r_agent) {
  __shared__ float relb[2][64 * 64];  // 2 x 16 KB
  __shared__ f16 tl[64 * 128];        // 16 KB
  __shared__ float alive[NA];
  const int bid = blockIdx.x;  // 0..511
  const int b = bid >> 4;
  const int i0 = (bid & 15) * 4;
  const int tid = threadIdx.x;
  const int w = tid >> 6, l = tid & 63, lr = l & 15, lh = l >> 4;

  auto stage = [&](int buf, int i) {
    const float* g = relations + (size_t)(b * NA + i) * NA * RLEN;
#pragma unroll
    for (int c4 = 0; c4 < 4; ++c4) {
      int c = w * 4 + c4;
      int srcf = c * 256 + ((l ^ ((4 * c + (l >> 4)) & 7)) * 4);
      gload_lds16(g + srcf, &relb[buf][c * 256]);
    }
  };

  stage(0, i0);
  if (tid < 64) alive[tid] = alive_mask[b * NA + tid];
  float bz[4];
#pragma unroll
  for (int n = 0; n < 4; ++n) bz[n] = re_b2[w * 64 + n * 16 + lr];
  f16x8 b1f[2][2];
#pragma unroll
  for (int kt = 0; kt < 2; ++kt)
#pragma unroll
    for (int n = 0; n < 2; ++n)
      b1f[kt][n] = *(const f16x8*)(pw1 + ((size_t)(kt * 8 + w * 2 + n) * 64 + l) * 8);
  float4 sp4[4][2];
  {
    const float* spp = sp_pk + (size_t)b * 8192;
#pragma unroll
    for (int mt = 0; mt < 4; ++mt)
#pragma unroll
      for (int n = 0; n < 2; ++n)
        sp4[mt][n] = *(const float4*)(spp + (size_t)((mt * 8 + w * 2 + n) * 64 + l) * 4);
  }
  const int aid = agent_id[0];
  const bool domax = (w >= 2);
  __syncthreads();

  for (int t = 0; t < 4; ++t) {
    const int cur = t & 1;
    f32x4 acc1[4][2];
#pragma unroll
    for (int mt = 0; mt < 4; ++mt)
#pragma unroll
      for (int n = 0; n < 2; ++n) acc1[mt][n] = (f32x4){0.f, 0.f, 0.f, 0.f};
#pragma unroll
    for (int mt = 0; mt < 4; ++mt) {
      int R = mt * 16 + lr;
      unsigned sw = ((unsigned)(R & 7)) << 4;
      f16x8 aK[2];
#pragma unroll
      for (int kt = 0; kt < 2; ++kt) {
        unsigned base = (unsigned)((R * 64 + kt * 32 + lh * 8) * 4);
        float4 v0 = *(const float4*)((char*)relb[cur] + (base ^ sw));
        float4 v1 = *(const float4*)((char*)relb[cur] + ((base + 16) ^ sw));
        aK[kt] = cvt8(v0, v1);
      }
#pragma unroll
      for (int kt = 0; kt < 2; ++kt)
#pragma unroll
        for (int n = 0; n < 2; ++n)
          acc1[mt][n] = __builtin_amdgcn_mfma_f32_16x16x32_f16(aK[kt], b1f[kt][n],
                                                               acc1[mt][n], 0, 0, 0);
    }
#pragma unroll
    for (int mt = 0; mt < 4; ++mt)
#pragma unroll
      for (int n = 0; n < 2; ++n) {
        int h = w * 32 + n * 16 + lr;
#pragma unroll
        for (int reg = 0; reg < 4; ++reg) {
          int j = mt * 16 + lh * 4 + reg;
          float v = fmaxf(acc1[mt][n][reg] + sp4[mt][n][reg], 0.f);
          unsigned off = (unsigned)((j * NH + h) * 2) ^ ((unsigned)(j & 7) << 4);
          *(f16*)((char*)tl + off) = (f16)v;
        }
      }
    __syncthreads();

    if (t < 3) stage(cur ^ 1, i0 + t + 1);

    f32x4 acc2[4][4];
#pragma unroll
    for (int mt = 0; mt < 4; ++mt)
#pragma unroll
      for (int n = 0; n < 4; ++n) acc2[mt][n] = (f32x4){0.f, 0.f, 0.f, 0.f};
#pragma unroll
    for (int kt2 = 0; kt2 < 4; ++kt2) {
      f16x8 a2[4];
#pragma unroll
      for (int mt = 0; mt < 4; ++mt) {
        int row = mt * 16 + lr;
        unsigned off = (unsigned)((row * 256 + kt2 * 64 + lh * 16)) ^ ((unsigned)(row & 7) << 4);
        a2[mt] = *(const f16x8*)((char*)tl + off);
      }
      f16x8 b2f[4];
#pragma unroll
      for (int n = 0; n < 4; ++n)
        b2f[n] = *(const f16x8*)(pw2 + ((size_t)(kt2 * 16 + w * 4 + n) * 64 + l) * 8);
#pragma unroll
      for (int mt = 0; mt < 4; ++mt)
#pragma unroll
        for (int n = 0; n < 4; ++n)
          acc2[mt][n] = __builtin_amdgcn_mfma_f32_16x16x32_f16(a2[mt], b2f[n], acc2[mt][n], 0, 0, 0);
    }

    const int i = i0 + t;
    const bool isagent = (i == aid);
    float red[4];
#pragma unroll
    for (int n = 0; n < 4; ++n) red[n] = 0.f;
#pragma unroll
    for (int n = 0; n < 4; ++n) {
      int col = w * 64 + n * 16 + lr;
      float bias = bz[n];
#pragma unroll
      for (int mt = 0; mt < 4; ++mt)
#pragma unroll
        for (int reg = 0; reg < 4; ++reg) {
          int j = mt * 16 + lh * 4 + reg;
          float rv = fmaxf(acc2[mt][n][reg] + bias, 0.f);
          float rm = rv * alive[j];
          red[n] = domax ? fmaxf(red[n], rm) : (red[n] + rm);
          if (isagent) r_agent[((size_t)b * NA + j) * 256 + col] = (f16)rv;
        }
    }
#pragma unroll
    for (int n = 0; n < 4; ++n) {
      float v = red[n];
      float v1 = __shfl_xor(v, 16, 64);
      v = domax ? fmaxf(v, v1) : v + v1;
      float v2 = __shfl_xor(v, 32, 64);
      v = domax ? fmaxf(v, v2) : v + v2;
      if (lh == 0) r_red[(size_t)(b * NA + i) * 256 + w * 64 + n * 16 + lr] = v;
    }
    __syncthreads();
  }
}

// ---------------------------------------------------------------------------
// K4m-lite (unchanged): 16 rows per block, grid 128. s_new only.
// ---------------------------------------------------------------------------
__global__ __launch_bounds__(256) void k4m(const float* __restrict__ s,
                                           const float* __restrict__ r_red,
                                           const float* __restrict__ ra_b,
                                           const f16* __restrict__ pra,
                                           float* __restrict__ s_new) {
  __shared__ f16 x3[16 * 384];
  const int row0 = blockIdx.x * 16;
  const int tid = threadIdx.x;
  const int w = tid >> 6, l = tid & 63, lr = l & 15, lh = l >> 4;

#pragma unroll
  for (int it = 0; it < 6; ++it) {
    int e = it * 1024 + tid * 4;
    int row = e / 384;
    int c = e - row * 384;
    float4 v;
    if (c < 128) {
      v = *(const float4*)(s + (size_t)(row0 + row) * NH + c);
    } else {
      v = *(const float4*)(r_red + (size_t)(row0 + row) * 256 + (c - 128));
      if (c < 256) { v.x *= (1.f / 64.f); v.y *= (1.f / 64.f); v.z *= (1.f / 64.f); v.w *= (1.f / 64.f); }
    }
    f16x4 hv;
    hv[0] = (f16)v.x; hv[1] = (f16)v.y; hv[2] = (f16)v.z; hv[3] = (f16)v.w;
    unsigned off = (unsigned)((row * 384 + c) * 2) ^ ((unsigned)(row & 7) << 4);
    *(f16x4*)((char*)x3 + off) = hv;
  }
  __syncthreads();

  f32x4 acc[2];
  acc[0] = (f32x4){0.f, 0.f, 0.f, 0.f};
  acc[1] = (f32x4){0.f, 0.f, 0.f, 0.f};
#pragma unroll
  for (int kt = 0; kt < 12; ++kt) {
    unsigned off = (unsigned)((lr * 384 + kt * 32 + lh * 8) * 2) ^ ((unsigned)(lr & 7) << 4);
    f16x8 aF = *(const f16x8*)((char*)x3 + off);
#pragma unroll
    for (int n = 0; n < 2; ++n) {
      f16x8 bF = *(const f16x8*)(pra + ((size_t)(kt * 8 + w * 2 + n) * 64 + l) * 8);
      acc[n] = __builtin_amdgcn_mfma_f32_16x16x32_f16(aF, bF, acc[n], 0, 0, 0);
    }
  }
#pragma unroll
  for (int n = 0; n < 2; ++n) {
    int h = w * 32 + n * 16 + lr;
    float bias = ra_b[h];
#pragma unroll
    for (int reg = 0; reg < 4; ++reg) {
      int j = lh * 4 + reg;
      s_new[(size_t)(row0 + j) * NH + h] = fmaxf(acc[n][reg] + bias, 0.f);
    }
  }
}

// ---------------------------------------------------------------------------
// K5mg: fused k5m + k5g. Blocks 0,1: ae-MFMA for 16 b's each + write special
// output rows (i==aid, i==act-16) + out_sel. Blocks 2..257: copy non-special
// rows (st=s_new, ps=0).
// ---------------------------------------------------------------------------
__global__ __launch_bounds__(256) void k5mg(const f16* __restrict__ r_agent,
                                            const float* __restrict__ s_new,
                                            const float* __restrict__ ae_b1,
                                            const float* __restrict__ ae_b2,
                                            const float* __restrict__ action_embed,
                                            const int* __restrict__ action,
                                            const int* __restrict__ agent_id,
                                            const f16* __restrict__ pae1a,
                                            const f16* __restrict__ pae1b,
                                            const f16* __restrict__ pae1c,
                                            const f16* __restrict__ pae2,
                                            float* __restrict__ out_state,
                                            float* __restrict__ out_sel,
                                            float* __restrict__ out_passive) {
  __shared__ f16 xa[16 * 512];       // 16 KB
  __shared__ f16 t1[16 * 128];       // 4 KB
  __shared__ float selL[16][128];    // 8 KB
  __shared__ float pasL[16][128];    // 8 KB
  __shared__ int actL[16];
  const int aid = agent_id[0];
  const int tid = threadIdx.x;

  if (blockIdx.x >= 2) {
    // ---- copy path: 1 float4 per thread, skip special rows ----
    int q = (blockIdx.x - 2) * 256 + tid;
    int idx = q * 4;
    int h = idx & 127;
    int row = idx >> 7;
    int b = row >> 6, i = row & 63;
    int act = action[b];
    bool special = (i == aid) || (act >= NE && i == act - NE);
    if (!special) {
      *(float4*)(out_state + idx) = *(const float4*)(s_new + idx);
      *(float4*)(out_passive + idx) = (float4){0.f, 0.f, 0.f, 0.f};
    }
    (void)h;
    return;
  }

  // ---- ae path: 16 b's per block ----
  const int b0 = blockIdx.x * 16;
  const int w = tid >> 6, l = tid & 63, lr = l & 15, lh = l >> 4;

  // gather stage: thread (row=tid&15, g=tid>>4) covers 32 k's
  {
    int row = tid & 15, g = tid >> 4;
    int bb = b0 + row;
    int act = action[bb];
    if (g == 0) actL[row] = act;
    int jj = act >= NE ? act - NE : 0;
    int k0 = g * 32;
    f16x8 vv[4];
    if (g < 8) {
      const f16* src = r_agent + ((size_t)bb * NA + jj) * 256 + k0;
#pragma unroll
      for (int c = 0; c < 4; ++c) vv[c] = *(const f16x8*)(src + c * 8);
    } else {
      const float* src = (g < 12) ? (s_new + ((size_t)bb * NA + jj) * NH + (g - 8) * 32)
                                  : (s_new + ((size_t)bb * NA + aid) * NH + (g - 12) * 32);
#pragma unroll
      for (int c = 0; c < 4; ++c)
        vv[c] = cvt8(*(const float4*)(src + c * 8), *(const float4*)(src + c * 8 + 4));
    }
#pragma unroll
    for (int c = 0; c < 4; ++c) {
      unsigned off = (unsigned)((row * 512 + k0 + c * 8) * 2) ^ ((unsigned)(row & 7) << 4);
      *(f16x8*)((char*)xa + off) = vv[c];
    }
  }
  __syncthreads();

  // layer1 K=512
  f32x4 acc[2];
  acc[0] = (f32x4){0.f, 0.f, 0.f, 0.f};
  acc[1] = (f32x4){0.f, 0.f, 0.f, 0.f};
#pragma unroll
  for (int kt = 0; kt < 16; ++kt) {
    unsigned off = (unsigned)((lr * 512 + kt * 32 + lh * 8) * 2) ^ ((unsigned)(lr & 7) << 4);
    f16x8 aF = *(const f16x8*)((char*)xa + off);
    const f16* pseg = (kt < 8) ? pae1a : (kt < 12) ? pae1b : pae1c;
    int ktl = (kt < 8) ? kt : (kt < 12) ? kt - 8 : kt - 12;
#pragma unroll
    for (int n = 0; n < 2; ++n) {
      f16x8 bF = *(const f16x8*)(pseg + ((size_t)(ktl * 8 + w * 2 + n) * 64 + l) * 8);
      acc[n] = __builtin_amdgcn_mfma_f32_16x16x32_f16(aF, bF, acc[n], 0, 0, 0);
    }
  }
#pragma unroll
  for (int n = 0; n < 2; ++n) {
    int h = w * 32 + n * 16 + lr;
    float bias = ae_b1[h];
#pragma unroll
    for (int reg = 0; reg < 4; ++reg) {
      int j = lh * 4 + reg;
      float v = fmaxf(acc[n][reg] + bias, 0.f);
      unsigned off = (unsigned)((j * NH + h) * 2) ^ ((unsigned)(j & 7) << 4);
      *(f16*)((char*)t1 + off) = (f16)v;
    }
  }
  __syncthreads();

  // layer2 K=128 N=256
  f32x4 acc2[4];
#pragma unroll
  for (int n = 0; n < 4; ++n) acc2[n] = (f32x4){0.f, 0.f, 0.f, 0.f};
#pragma unroll
  for (int kt = 0; kt < 4; ++kt) {
    unsigned off = (unsigned)((lr * NH + kt * 32 + lh * 8) * 2) ^ ((unsigned)(lr & 7) << 4);
    f16x8 aF = *(const f16x8*)((char*)t1 + off);
#pragma unroll
    for (int n = 0; n < 4; ++n) {
      f16x8 bF = *(const f16x8*)(pae2 + ((size_t)(kt * 16 + w * 4 + n) * 64 + l) * 8);
      acc2[n] = __builtin_amdgcn_mfma_f32_16x16x32_f16(aF, bF, acc2[n], 0, 0, 0);
    }
  }
#pragma unroll
  for (int n = 0; n < 4; ++n) {
    int col = w * 64 + n * 16 + lr;
    float bias = ae_b2[col];
#pragma unroll
    for (int reg = 0; reg < 4; ++reg) {
      int row = lh * 4 + reg;
      int act = actL[row];
      float v = fmaxf(acc2[n][reg] + bias, 0.f);
      if (col < NH) {
        selL[row][col] = (act < NE) ? action_embed[act * NH + col] : v;
      } else {
        pasL[row][col - NH] = (act < NE) ? 0.f : v;
      }
    }
  }
  __syncthreads();

  // write out_sel + special output rows
  for (int e = tid; e < 16 * 128; e += 256) {
    int rb = e >> 7, c = e & 127;
    int bb = b0 + rb;
    int act = actL[rb];
    float sv = selL[rb][c], pv = pasL[rb][c];
    out_sel[bb * NH + c] = sv;
    size_t ia = ((size_t)bb * NA + aid) * NH + c;
    bool paid = (act >= NE) && (act - NE == aid);
    out_state[ia] = s_new[ia] + sv + (paid ? pv : 0.f);
    out_passive[ia] = paid ? pv : 0.f;
    if (act >= NE && act - NE != aid) {
      size_t ip = ((size_t)bb * NA + (act - NE)) * NH + c;
      out_state[ip] = s_new[ip] + pv;
      out_passive[ip] = pv;
    }
  }
}

// ---------------------------------------------------------------------------
extern "C" void kernel_launch(void* const* d_in, const int* in_sizes, int n_in,
                              void* d_out, int out_size, void* d_ws, size_t ws_size,
                              hipStream_t stream) {
  (void)in_sizes; (void)n_in; (void)out_size; (void)ws_size;
  const float* states       = (const float*)d_in[0];
  const float* relations    = (const float*)d_in[1];
  const float* alive_mask   = (const float*)d_in[2];
  const float* se_w1        = (const float*)d_in[3];
  const float* se_b1        = (const float*)d_in[4];
  const float* se_w2        = (const float*)d_in[5];
  const float* se_b2        = (const float*)d_in[6];
  const float* re_w1        = (const float*)d_in[7];
  const float* re_b1        = (const float*)d_in[8];
  const float* re_w2        = (const float*)d_in[9];
  const float* re_b2        = (const float*)d_in[10];
  const float* ra_w         = (const float*)d_in[11];
  const float* ra_b         = (const float*)d_in[12];
  const float* ae_w1        = (const float*)d_in[13];
  const float* ae_b1        = (const float*)d_in[14];
  const float* ae_w2        = (const float*)d_in[15];
  const float* ae_b2        = (const float*)d_in[16];
  const float* action_embed = (const float*)d_in[17];
  const int*   action       = (const int*)d_in[19];
  const int*   agent_id     = (const int*)d_in[20];
  float* out = (float*)d_out;

  // workspace layout (float elements)
  float* wsf     = (float*)d_ws;
  float* s       = wsf;               // 262144
  float* sp_pk   = wsf + 262144;      // 262144
  float* r_red   = wsf + 524288;      // 524288
  float* s_new   = wsf + 1048576;     // 262144
  f16*   wsh     = (f16*)(wsf + 1318912);
  f16*   r_agent = wsh;               // 524288 f16
  f16*   pk      = wsh + 524288;      // 253952 f16 packed weights
  f16*   pw_re1a = pk;
  f16*   pw_re2  = pk + 8192;
  f16*   pw_ra   = pk + 106496;
  f16*   pw_ae1b = pk + 155648;
  f16*   pw_ae1c = pk + 172032;
  f16*   pw_ae1a = pk + 188416;
  f16*   pw_ae2  = pk + 221184;

  ka<<<192, 256, 0, stream>>>(states, se_w1, se_b1, se_w2, se_b2, re_w1, re_b1,
                              re_w2, ra_w, ae_w1, ae_w2, s, sp_pk, pk);
  k3_rel<<<512, 256, 0, stream>>>(relations, alive_mask, sp_pk, re_b2, pw_re1a, pw_re2,
                                  agent_id, r_red, r_agent);
  k4m<<<128, 256, 0, stream>>>(s, r_red, ra_b, pw_ra, s_new);
  k5mg<<<258, 256, 0, stream>>>(r_agent, s_new, ae_b1, ae_b2, action_embed, action,
                                agent_id, pw_ae1a, pw_ae1b, pw_ae1c, pw_ae2,
                                out, out + 262144, out + 266240);
}

// Round 9
// 167.369 us; speedup vs baseline: 1.0210x; 1.0210x over previous
//
#include <hip/hip_runtime.h>

// Problem dims
#define NB 32
#define NA 64
#define SLEN 256
#define NH 128
#define RLEN 64
#define NE 16

typedef _Float16 f16;
typedef _Float16 f16x8 __attribute__((ext_vector_type(8)));
typedef _Float16 f16x4 __attribute__((ext_vector_type(4)));
typedef float f32x4 __attribute__((ext_vector_type(4)));

__device__ inline f16x8 cvt8(float4 a, float4 b) {
  f16x8 r;
  r[0] = (f16)a.x; r[1] = (f16)a.y; r[2] = (f16)a.z; r[3] = (f16)a.w;
  r[4] = (f16)b.x; r[5] = (f16)b.y; r[6] = (f16)b.z; r[7] = (f16)b.w;
  return r;
}

// Gather one MFMA B-fragment directly from a raw row-major weight matrix.
__device__ inline f16x8 gatherW(const float* __restrict__ W, int ld, int row0, int col) {
  f16x8 r;
#pragma unroll
  for (int t = 0; t < 8; ++t) r[t] = (f16)W[(size_t)(row0 + t) * ld + col];
  return r;
}

// ---------------------------------------------------------------------------
// KA: three concurrent paths.
//   blocks 0..127   : k1m s-MLP (direct-gather weights) -> s, sp_pk
//   blocks 128..191 : pack k3/k5 weights into fp16 fragment order
//   blocks 192..703 : cast relations fp32 -> fp16 (rel16), pure streaming
// ---------------------------------------------------------------------------
__global__ __launch_bounds__(256) void ka(const float* __restrict__ states,
                                          const float* __restrict__ relations,
                                          const float* __restrict__ se_w1,
                                          const float* __restrict__ se_b1,
                                          const float* __restrict__ se_w2,
                                          const float* __restrict__ se_b2,
                                          const float* __restrict__ re_w1,
                                          const float* __restrict__ re_b1,
                                          const float* __restrict__ re_w2,
                                          const float* __restrict__ ra_w,
                                          const float* __restrict__ ae_w1,
                                          const float* __restrict__ ae_w2,
                                          float* __restrict__ s_out,
                                          float* __restrict__ sp_pk,
                                          f16* __restrict__ pk,
                                          f16* __restrict__ rel16) {
  __shared__ f16 t1[16 * 128];
  __shared__ f16 t2[16 * 128];
  if (blockIdx.x >= 192) {
    // ---- cast path: 512 blocks x 4096 float4 ----
    const int cb = blockIdx.x - 192;
    const float4* r4 = (const float4*)relations;
    f16x4* o4 = (f16x4*)rel16;
#pragma unroll
    for (int it = 0; it < 16; ++it) {
      int i4 = cb * 4096 + it * 256 + threadIdx.x;
      float4 v = r4[i4];
      f16x4 h;
      h[0] = (f16)v.x; h[1] = (f16)v.y; h[2] = (f16)v.z; h[3] = (f16)v.w;
      o4[i4] = h;
    }
    return;
  }
  if (blockIdx.x >= 128) {
    // ---- pack path ----
    int t0 = (blockIdx.x - 128) * 256 + threadIdx.x;
    for (int idx = t0; idx < 188416; idx += 64 * 256) {
      const float* src; int ro, N, ld, base, dst;
      if (idx < 8192)        { src = re_w1; ro = 0;   N = 128; ld = 128; base = 0;      dst = 0; }
      else if (idx < 40960)  { src = re_w2; ro = 0;   N = 256; ld = 256; base = 8192;   dst = 8192; }
      else if (idx < 90112)  { src = ra_w;  ro = 0;   N = 128; ld = 128; base = 40960;  dst = 106496; }
      else if (idx < 106496) { src = ae_w1; ro = 256; N = 128; ld = 128; base = 90112;  dst = 155648; }
      else if (idx < 122880) { src = ae_w1; ro = 384; N = 128; ld = 128; base = 106496; dst = 172032; }
      else if (idx < 155648) { src = ae_w1; ro = 0;   N = 128; ld = 128; base = 122880; dst = 188416; }
      else                   { src = ae_w2; ro = 0;   N = 256; ld = 256; base = 155648; dst = 221184; }
      int li = idx - base;
      int t = li & 7, l = (li >> 3) & 63, rem = li >> 9;
      int NT = N >> 4;
      int nt = rem % NT, kt = rem / NT;
      int k = kt * 32 + (l >> 4) * 8 + t;
      int n = nt * 16 + (l & 15);
      pk[dst + li] = (f16)src[(size_t)(ro + k) * ld + n];
    }
    return;
  }
  // ---- k1m path: 16 rows per block ----
  const int row0 = blockIdx.x * 16;
  const int tid = threadIdx.x;
  const int w = tid >> 6, l = tid & 63, lr = l & 15, lh = l >> 4;

  f32x4 acc[2];
  acc[0] = (f32x4){0.f, 0.f, 0.f, 0.f};
  acc[1] = (f32x4){0.f, 0.f, 0.f, 0.f};

  // layer1 K=256
#pragma unroll
  for (int kt = 0; kt < 8; ++kt) {
    const float* p = states + (size_t)(row0 + lr) * SLEN + kt * 32 + lh * 8;
    f16x8 aF = cvt8(*(const float4*)p, *(const float4*)(p + 4));
#pragma unroll
    for (int n = 0; n < 2; ++n) {
      f16x8 bF = gatherW(se_w1, 128, kt * 32 + lh * 8, (w * 2 + n) * 16 + lr);
      acc[n] = __builtin_amdgcn_mfma_f32_16x16x32_f16(aF, bF, acc[n], 0, 0, 0);
    }
  }
#pragma unroll
  for (int n = 0; n < 2; ++n) {
    int h = w * 32 + n * 16 + lr;
    float bias = se_b1[h];
#pragma unroll
    for (int reg = 0; reg < 4; ++reg) {
      int j = lh * 4 + reg;
      float v = fmaxf(acc[n][reg] + bias, 0.f);
      unsigned off = (unsigned)((j * NH + h) * 2) ^ ((unsigned)(j & 7) << 4);
      *(f16*)((char*)t1 + off) = (f16)v;
    }
  }
  __syncthreads();

  // layer2 K=128
  acc[0] = (f32x4){0.f, 0.f, 0.f, 0.f};
  acc[1] = (f32x4){0.f, 0.f, 0.f, 0.f};
#pragma unroll
  for (int kt = 0; kt < 4; ++kt) {
    unsigned off = (unsigned)((lr * NH + kt * 32 + lh * 8) * 2) ^ ((unsigned)(lr & 7) << 4);
    f16x8 aF = *(const f16x8*)((char*)t1 + off);
#pragma unroll
    for (int n = 0; n < 2; ++n) {
      f16x8 bF = gatherW(se_w2, 128, kt * 32 + lh * 8, (w * 2 + n) * 16 + lr);
      acc[n] = __builtin_amdgcn_mfma_f32_16x16x32_f16(aF, bF, acc[n], 0, 0, 0);
    }
  }
#pragma unroll
  for (int n = 0; n < 2; ++n) {
    int h = w * 32 + n * 16 + lr;
    float bias = se_b2[h];
#pragma unroll
    for (int reg = 0; reg < 4; ++reg) {
      int j = lh * 4 + reg;
      float v = fmaxf(acc[n][reg] + bias, 0.f);
      s_out[(size_t)(row0 + j) * NH + h] = v;
      unsigned off = (unsigned)((j * NH + h) * 2) ^ ((unsigned)(j & 7) << 4);
      *(f16*)((char*)t2 + off) = (f16)v;
    }
  }
  __syncthreads();

  // proj K=128: sproj1 = s @ re_w1[64:192] + re_b1, packed store (k3 C-frag order)
  acc[0] = (f32x4){0.f, 0.f, 0.f, 0.f};
  acc[1] = (f32x4){0.f, 0.f, 0.f, 0.f};
#pragma unroll
  for (int kt = 0; kt < 4; ++kt) {
    unsigned off = (unsigned)((lr * NH + kt * 32 + lh * 8) * 2) ^ ((unsigned)(lr & 7) << 4);
    f16x8 aF = *(const f16x8*)((char*)t2 + off);
#pragma unroll
    for (int n = 0; n < 2; ++n) {
      f16x8 bF = gatherW(re_w1, 128, 64 + kt * 32 + lh * 8, (w * 2 + n) * 16 + lr);
      acc[n] = __builtin_amdgcn_mfma_f32_16x16x32_f16(aF, bF, acc[n], 0, 0, 0);
    }
  }
  const int bb = row0 >> 6;
  const int mtile = (row0 & 63) >> 4;
#pragma unroll
  for (int n = 0; n < 2; ++n) {
    int h = w * 32 + n * 16 + lr;
    float bias = re_b1[h];
    float4 outv;
#pragma unroll
    for (int reg = 0; reg < 4; ++reg) outv[reg] = acc[n][reg] + bias;
    *(float4*)(sp_pk + ((size_t)((bb * 4 + mtile) * 8 + w * 2 + n) * 64 + l) * 4) = outv;
  }
}

// ---------------------------------------------------------------------------
// K3 v6: one (b,i) tile per block, grid 2048. A-operand = pre-cast fp16
// relations, loaded as direct 16B f16x8 fragments (no cvt, no staging).
// LDS = tl only (16.3 KB).
// ---------------------------------------------------------------------------
__global__ __launch_bounds__(256) void k3_rel(const f16* __restrict__ rel16,
                                              const float* __restrict__ alive_mask,
                                              const float* __restrict__ sp_pk,
                                              const float* __restrict__ re_b2,
                                              const f16* __restrict__ pw1,
                                              const f16* __restrict__ pw2,
                                              const int* __restrict__ agent_id,
                                              float* __restrict__ r_red,
                                              f16* __restrict__ r_agent) {
  __shared__ f16 tl[64 * 128];  // 16 KB
  __shared__ float alive[NA];
  const int bid = blockIdx.x;  // 0..2047
  const int b = bid >> 6, i = bid & 63;
  const int tid = threadIdx.x;
  const int w = tid >> 6, l = tid & 63, lr = l & 15, lh = l >> 4;

  if (tid < 64) alive[tid] = alive_mask[b * NA + tid];
  float bz[4];
#pragma unroll
  for (int n = 0; n < 4; ++n) bz[n] = re_b2[w * 64 + n * 16 + lr];

  // A fragments: direct f16x8 loads from rel16 tile
  const f16* rp = rel16 + (size_t)bid * (NA * RLEN);
  f16x8 a1[4][2];
#pragma unroll
  for (int mt = 0; mt < 4; ++mt)
#pragma unroll
    for (int kt = 0; kt < 2; ++kt)
      a1[mt][kt] = *(const f16x8*)(rp + (mt * 16 + lr) * RLEN + kt * 32 + lh * 8);
  f16x8 b1f[2][2];
#pragma unroll
  for (int kt = 0; kt < 2; ++kt)
#pragma unroll
    for (int n = 0; n < 2; ++n)
      b1f[kt][n] = *(const f16x8*)(pw1 + ((size_t)(kt * 8 + w * 2 + n) * 64 + l) * 8);
  float4 sp4[4][2];
  {
    const float* spp = sp_pk + (size_t)b * 8192;
#pragma unroll
    for (int mt = 0; mt < 4; ++mt)
#pragma unroll
      for (int n = 0; n < 2; ++n)
        sp4[mt][n] = *(const float4*)(spp + (size_t)((mt * 8 + w * 2 + n) * 64 + l) * 4);
  }

  f32x4 acc1[4][2];
#pragma unroll
  for (int mt = 0; mt < 4; ++mt)
#pragma unroll
    for (int n = 0; n < 2; ++n) acc1[mt][n] = (f32x4){0.f, 0.f, 0.f, 0.f};
#pragma unroll
  for (int kt = 0; kt < 2; ++kt)
#pragma unroll
    for (int mt = 0; mt < 4; ++mt)
#pragma unroll
      for (int n = 0; n < 2; ++n)
        acc1[mt][n] = __builtin_amdgcn_mfma_f32_16x16x32_f16(a1[mt][kt], b1f[kt][n],
                                                             acc1[mt][n], 0, 0, 0);

  // epilogue1: + sproj1 fragment (re_b1 folded), relu, fp16 swizzled LDS
#pragma unroll
  for (int mt = 0; mt < 4; ++mt)
#pragma unroll
    for (int n = 0; n < 2; ++n) {
      int h = w * 32 + n * 16 + lr;
#pragma unroll
      for (int reg = 0; reg < 4; ++reg) {
        int j = mt * 16 + lh * 4 + reg;
        float v = fmaxf(acc1[mt][n][reg] + sp4[mt][n][reg], 0.f);
        unsigned off = (unsigned)((j * NH + h) * 2) ^ ((unsigned)(j & 7) << 4);
        *(f16*)((char*)tl + off) = (f16)v;
      }
    }
  __syncthreads();

  // layer2: wave w owns output cols [w*64, w*64+64)
  f32x4 acc2[4][4];
#pragma unroll
  for (int mt = 0; mt < 4; ++mt)
#pragma unroll
    for (int n = 0; n < 4; ++n) acc2[mt][n] = (f32x4){0.f, 0.f, 0.f, 0.f};
#pragma unroll
  for (int kt2 = 0; kt2 < 4; ++kt2) {
    f16x8 a2[4];
#pragma unroll
    for (int mt = 0; mt < 4; ++mt) {
      int row = mt * 16 + lr;
      unsigned off = (unsigned)((row * 256 + kt2 * 64 + lh * 16)) ^ ((unsigned)(row & 7) << 4);
      a2[mt] = *(const f16x8*)((char*)tl + off);
    }
    f16x8 b2f[4];
#pragma unroll
    for (int n = 0; n < 4; ++n)
      b2f[n] = *(const f16x8*)(pw2 + ((size_t)(kt2 * 16 + w * 4 + n) * 64 + l) * 8);
#pragma unroll
    for (int mt = 0; mt < 4; ++mt)
#pragma unroll
      for (int n = 0; n < 4; ++n)
        acc2[mt][n] = __builtin_amdgcn_mfma_f32_16x16x32_f16(a2[mt], b2f[n], acc2[mt][n], 0, 0, 0);
  }

  // epilogue2: bias+relu, masked sum/max over j, agent slice store
  const int aid = agent_id[0];
  const bool isagent = (i == aid);
  const bool domax = (w >= 2);
  float red[4];
#pragma unroll
  for (int n = 0; n < 4; ++n) red[n] = 0.f;
#pragma unroll
  for (int n = 0; n < 4; ++n) {
    int col = w * 64 + n * 16 + lr;
    float bias = bz[n];
#pragma unroll
    for (int mt = 0; mt < 4; ++mt)
#pragma unroll
      for (int reg = 0; reg < 4; ++reg) {
        int j = mt * 16 + lh * 4 + reg;
        float rv = fmaxf(acc2[mt][n][reg] + bias, 0.f);
        float rm = rv * alive[j];
        red[n] = domax ? fmaxf(red[n], rm) : (red[n] + rm);
        if (isagent) r_agent[((size_t)b * NA + j) * 256 + col] = (f16)rv;
      }
  }
#pragma unroll
  for (int n = 0; n < 4; ++n) {
    float v = red[n];
    float v1 = __shfl_xor(v, 16, 64);
    v = domax ? fmaxf(v, v1) : v + v1;
    float v2 = __shfl_xor(v, 32, 64);
    v = domax ? fmaxf(v, v2) : v + v2;
    if (lh == 0) r_red[(size_t)bid * 256 + w * 64 + n * 16 + lr] = v;
  }
}

// ---------------------------------------------------------------------------
// K4m-lite (unchanged): 16 rows per block, grid 128. s_new only.
// ---------------------------------------------------------------------------
__global__ __launch_bounds__(256) void k4m(const float* __restrict__ s,
                                           const float* __restrict__ r_red,
                                           const float* __restrict__ ra_b,
                                           const f16* __restrict__ pra,
                                           float* __restrict__ s_new) {
  __shared__ f16 x3[16 * 384];
  const int row0 = blockIdx.x * 16;
  const int tid = threadIdx.x;
  const int w = tid >> 6, l = tid & 63, lr = l & 15, lh = l >> 4;

#pragma unroll
  for (int it = 0; it < 6; ++it) {
    int e = it * 1024 + tid * 4;
    int row = e / 384;
    int c = e - row * 384;
    float4 v;
    if (c < 128) {
      v = *(const float4*)(s + (size_t)(row0 + row) * NH + c);
    } else {
      v = *(const float4*)(r_red + (size_t)(row0 + row) * 256 + (c - 128));
      if (c < 256) { v.x *= (1.f / 64.f); v.y *= (1.f / 64.f); v.z *= (1.f / 64.f); v.w *= (1.f / 64.f); }
    }
    f16x4 hv;
    hv[0] = (f16)v.x; hv[1] = (f16)v.y; hv[2] = (f16)v.z; hv[3] = (f16)v.w;
    unsigned off = (unsigned)((row * 384 + c) * 2) ^ ((unsigned)(row & 7) << 4);
    *(f16x4*)((char*)x3 + off) = hv;
  }
  __syncthreads();

  f32x4 acc[2];
  acc[0] = (f32x4){0.f, 0.f, 0.f, 0.f};
  acc[1] = (f32x4){0.f, 0.f, 0.f, 0.f};
#pragma unroll
  for (int kt = 0; kt < 12; ++kt) {
    unsigned off = (unsigned)((lr * 384 + kt * 32 + lh * 8) * 2) ^ ((unsigned)(lr & 7) << 4);
    f16x8 aF = *(const f16x8*)((char*)x3 + off);
#pragma unroll
    for (int n = 0; n < 2; ++n) {
      f16x8 bF = *(const f16x8*)(pra + ((size_t)(kt * 8 + w * 2 + n) * 64 + l) * 8);
      acc[n] = __builtin_amdgcn_mfma_f32_16x16x32_f16(aF, bF, acc[n], 0, 0, 0);
    }
  }
#pragma unroll
  for (int n = 0; n < 2; ++n) {
    int h = w * 32 + n * 16 + lr;
    float bias = ra_b[h];
#pragma unroll
    for (int reg = 0; reg < 4; ++reg) {
      int j = lh * 4 + reg;
      s_new[(size_t)(row0 + j) * NH + h] = fmaxf(acc[n][reg] + bias, 0.f);
    }
  }
}

// ---------------------------------------------------------------------------
// K5mg (unchanged): blocks 0,1 ae-MFMA + special rows; blocks 2..257 copy.
// ---------------------------------------------------------------------------
__global__ __launch_bounds__(256) void k5mg(const f16* __restrict__ r_agent,
                                            const float* __restrict__ s_new,
                                            const float* __restrict__ ae_b1,
                                            const float* __restrict__ ae_b2,
                                            const float* __restrict__ action_embed,
                                            const int* __restrict__ action,
                                            const int* __restrict__ agent_id,
                                            const f16* __restrict__ pae1a,
                                            const f16* __restrict__ pae1b,
                                            const f16* __restrict__ pae1c,
                                            const f16* __restrict__ pae2,
                                            float* __restrict__ out_state,
                                            float* __restrict__ out_sel,
                                            float* __restrict__ out_passive) {
  __shared__ f16 xa[16 * 512];
  __shared__ f16 t1[16 * 128];
  __shared__ float selL[16][128];
  __shared__ float pasL[16][128];
  __shared__ int actL[16];
  const int aid = agent_id[0];
  const int tid = threadIdx.x;

  if (blockIdx.x >= 2) {
    int q = (blockIdx.x - 2) * 256 + tid;
    int idx = q * 4;
    int row = idx >> 7;
    int b = row >> 6, i = row & 63;
    int act = action[b];
    bool special = (i == aid) || (act >= NE && i == act - NE);
    if (!special) {
      *(float4*)(out_state + idx) = *(const float4*)(s_new + idx);
      *(float4*)(out_passive + idx) = (float4){0.f, 0.f, 0.f, 0.f};
    }
    return;
  }

  const int b0 = blockIdx.x * 16;
  const int w = tid >> 6, l = tid & 63, lr = l & 15, lh = l >> 4;

  {
    int row = tid & 15, g = tid >> 4;
    int bb = b0 + row;
    int act = action[bb];
    if (g == 0) actL[row] = act;
    int jj = act >= NE ? act - NE : 0;
    int k0 = g * 32;
    f16x8 vv[4];
    if (g < 8) {
      const f16* src = r_agent + ((size_t)bb * NA + jj) * 256 + k0;
#pragma unroll
      for (int c = 0; c < 4; ++c) vv[c] = *(const f16x8*)(src + c * 8);
    } else {
      const float* src = (g < 12) ? (s_new + ((size_t)bb * NA + jj) * NH + (g - 8) * 32)
                                  : (s_new + ((size_t)bb * NA + aid) * NH + (g - 12) * 32);
#pragma unroll
      for (int c = 0; c < 4; ++c)
        vv[c] = cvt8(*(const float4*)(src + c * 8), *(const float4*)(src + c * 8 + 4));
    }
#pragma unroll
    for (int c = 0; c < 4; ++c) {
      unsigned off = (unsigned)((row * 512 + k0 + c * 8) * 2) ^ ((unsigned)(row & 7) << 4);
      *(f16x8*)((char*)xa + off) = vv[c];
    }
  }
  __syncthreads();

  f32x4 acc[2];
  acc[0] = (f32x4){0.f, 0.f, 0.f, 0.f};
  acc[1] = (f32x4){0.f, 0.f, 0.f, 0.f};
#pragma unroll
  for (int kt = 0; kt < 16; ++kt) {
    unsigned off = (unsigned)((lr * 512 + kt * 32 + lh * 8) * 2) ^ ((unsigned)(lr & 7) << 4);
    f16x8 aF = *(const f16x8*)((char*)xa + off);
    const f16* pseg = (kt < 8) ? pae1a : (kt < 12) ? pae1b : pae1c;
    int ktl = (kt < 8) ? kt : (kt < 12) ? kt - 8 : kt - 12;
#pragma unroll
    for (int n = 0; n < 2; ++n) {
      f16x8 bF = *(const f16x8*)(pseg + ((size_t)(ktl * 8 + w * 2 + n) * 64 + l) * 8);
      acc[n] = __builtin_amdgcn_mfma_f32_16x16x32_f16(aF, bF, acc[n], 0, 0, 0);
    }
  }
#pragma unroll
  for (int n = 0; n < 2; ++n) {
    int h = w * 32 + n * 16 + lr;
    float bias = ae_b1[h];
#pragma unroll
    for (int reg = 0; reg < 4; ++reg) {
      int j = lh * 4 + reg;
      float v = fmaxf(acc[n][reg] + bias, 0.f);
      unsigned off = (unsigned)((j * NH + h) * 2) ^ ((unsigned)(j & 7) << 4);
      *(f16*)((char*)t1 + off) = (f16)v;
    }
  }
  __syncthreads();

  f32x4 acc2[4];
#pragma unroll
  for (int n = 0; n < 4; ++n) acc2[n] = (f32x4){0.f, 0.f, 0.f, 0.f};
#pragma unroll
  for (int kt = 0; kt < 4; ++kt) {
    unsigned off = (unsigned)((lr * NH + kt * 32 + lh * 8) * 2) ^ ((unsigned)(lr & 7) << 4);
    f16x8 aF = *(const f16x8*)((char*)t1 + off);
#pragma unroll
    for (int n = 0; n < 4; ++n) {
      f16x8 bF = *(const f16x8*)(pae2 + ((size_t)(kt * 16 + w * 4 + n) * 64 + l) * 8);
      acc2[n] = __builtin_amdgcn_mfma_f32_16x16x32_f16(aF, bF, acc2[n], 0, 0, 0);
    }
  }
#pragma unroll
  for (int n = 0; n < 4; ++n) {
    int col = w * 64 + n * 16 + lr;
    float bias = ae_b2[col];
#pragma unroll
    for (int reg = 0; reg < 4; ++reg) {
      int row = lh * 4 + reg;
      int act = actL[row];
      float v = fmaxf(acc2[n][reg] + bias, 0.f);
      if (col < NH) {
        selL[row][col] = (act < NE) ? action_embed[act * NH + col] : v;
      } else {
        pasL[row][col - NH] = (act < NE) ? 0.f : v;
      }
    }
  }
  __syncthreads();

  for (int e = tid; e < 16 * 128; e += 256) {
    int rb = e >> 7, c = e & 127;
    int bb = b0 + rb;
    int act = actL[rb];
    float sv = selL[rb][c], pv = pasL[rb][c];
    out_sel[bb * NH + c] = sv;
    size_t ia = ((size_t)bb * NA + aid) * NH + c;
    bool paid = (act >= NE) && (act - NE == aid);
    out_state[ia] = s_new[ia] + sv + (paid ? pv : 0.f);
    out_passive[ia] = paid ? pv : 0.f;
    if (act >= NE && act - NE != aid) {
      size_t ip = ((size_t)bb * NA + (act - NE)) * NH + c;
      out_state[ip] = s_new[ip] + pv;
      out_passive[ip] = pv;
    }
  }
}

// ---------------------------------------------------------------------------
extern "C" void kernel_launch(void* const* d_in, const int* in_sizes, int n_in,
                              void* d_out, int out_size, void* d_ws, size_t ws_size,
                              hipStream_t stream) {
  (void)in_sizes; (void)n_in; (void)out_size; (void)ws_size;
  const float* states       = (const float*)d_in[0];
  const float* relations    = (const float*)d_in[1];
  const float* alive_mask   = (const float*)d_in[2];
  const float* se_w1        = (const float*)d_in[3];
  const float* se_b1        = (const float*)d_in[4];
  const float* se_w2        = (const float*)d_in[5];
  const float* se_b2        = (const float*)d_in[6];
  const float* re_w1        = (const float*)d_in[7];
  const float* re_b1        = (const float*)d_in[8];
  const float* re_w2        = (const float*)d_in[9];
  const float* re_b2        = (const float*)d_in[10];
  const float* ra_w         = (const float*)d_in[11];
  const float* ra_b         = (const float*)d_in[12];
  const float* ae_w1        = (const float*)d_in[13];
  const float* ae_b1        = (const float*)d_in[14];
  const float* ae_w2        = (const float*)d_in[15];
  const float* ae_b2        = (const float*)d_in[16];
  const float* action_embed = (const float*)d_in[17];
  const int*   action       = (const int*)d_in[19];
  const int*   agent_id     = (const int*)d_in[20];
  float* out = (float*)d_out;

  // workspace layout (float elements)
  float* wsf     = (float*)d_ws;
  float* s       = wsf;               // 262144
  float* sp_pk   = wsf + 262144;      // 262144
  float* r_red   = wsf + 524288;      // 524288
  float* s_new   = wsf + 1048576;     // 262144
  f16*   wsh     = (f16*)(wsf + 1318912);
  f16*   r_agent = wsh;               // 524288 f16
  f16*   pk      = wsh + 524288;      // 253952 f16 packed weights
  f16*   rel16   = wsh + 524288 + 253952;  // 8388608 f16 (cast relations)
  f16*   pw_re1a = pk;
  f16*   pw_re2  = pk + 8192;
  f16*   pw_ra   = pk + 106496;
  f16*   pw_ae1b = pk + 155648;
  f16*   pw_ae1c = pk + 172032;
  f16*   pw_ae1a = pk + 188416;
  f16*   pw_ae2  = pk + 221184;

  ka<<<704, 256, 0, stream>>>(states, relations, se_w1, se_b1, se_w2, se_b2,
                              re_w1, re_b1, re_w2, ra_w, ae_w1, ae_w2,
                              s, sp_pk, pk, rel16);
  k3_rel<<<2048, 256, 0, stream>>>(rel16, alive_mask, sp_pk, re_b2, pw_re1a, pw_re2,
                                   agent_id, r_red, r_agent);
  k4m<<<128, 256, 0, stream>>>(s, r_red, ra_b, pw_ra, s_new);
  k5mg<<<258, 256, 0, stream>>>(r_agent, s_new, ae_b1, ae_b2, action_embed, action,
                                agent_id, pw_ae1a, pw_ae1b, pw_ae1c, pw_ae2,
                                out, out + 262144, out + 266240);
}